// Round 13
// baseline (300.787 us; speedup 1.0000x reference)
//
#include <hip/hip_runtime.h>
#include <math.h>

typedef unsigned short ushort_t;
typedef __attribute__((ext_vector_type(8))) short bf16x8;
typedef __attribute__((ext_vector_type(4))) float f32x4;

constexpr int kD      = 768;
constexpr int kNH     = 12;
constexpr int kDK     = 64;
constexpr int kFF     = 3072;
constexpr int kL      = 1024;
constexpr int kRows   = 2048;     // B * L
constexpr float kEPS  = 1e-5f;

__device__ __forceinline__ ushort_t f2bf(float f) {
    union { float f; unsigned u; } v; v.f = f;
    unsigned r = (v.u + 0x7fffu + ((v.u >> 16) & 1u)) >> 16;
    return (ushort_t)r;
}
__device__ __forceinline__ float bf2f(ushort_t u) {
    union { unsigned u; float f; } v; v.u = ((unsigned)u) << 16; return v.f;
}

#define GL_LDS(gp, lp) __builtin_amdgcn_global_load_lds( \
    (const __attribute__((address_space(1))) void*)(gp), \
    (__attribute__((address_space(3))) void*)(lp), 16, 0, 0)

// ---------------------------------------------------------------------------
// bf16 MFMA GEMM (m97 structure): 128x128 tile, BK=32, 4 waves.
// ---------------------------------------------------------------------------
template<int RELU, int OUTBF, int ADDBIAS>
__device__ __forceinline__ void gemm_body(const ushort_t* __restrict__ A,
                                          const ushort_t* __restrict__ WT,
                                          const float* __restrict__ bias,
                                          void* __restrict__ Cout,
                                          int N, int K, int row0, int col0,
                                          int kbeg, int kend)
{
    __shared__ ushort_t lds[8192];
    ushort_t* As = lds;
    ushort_t* Bs = lds + 4096;

    const int tid  = threadIdx.x;
    const int lane = tid & 63;
    const int wave = tid >> 6;
    const int wrow = (wave & 1) * 64;
    const int wcol = (wave >> 1) * 64;

    const int srow = wave * 16 + (lane >> 2);
    const int sk   = (lane & 3) * 8;
    const ushort_t* ga0 = A  + (size_t)(row0 + srow)      * K + sk;
    const ushort_t* ga1 = A  + (size_t)(row0 + srow + 64) * K + sk;
    const ushort_t* gb0 = WT + (size_t)(col0 + srow)      * K + sk;
    const ushort_t* gb1 = WT + (size_t)(col0 + srow + 64) * K + sk;
    ushort_t* la0 = As + wave * 512;
    ushort_t* la1 = As + 2048 + wave * 512;
    ushort_t* lb0 = Bs + wave * 512;
    ushort_t* lb1 = Bs + 2048 + wave * 512;

    const int fl = lane & 15, fq = lane >> 4;
    const ushort_t* fa[4];
    const ushort_t* fb[4];
    #pragma unroll
    for (int i = 0; i < 4; ++i) {
        fa[i] = As + (wrow + i * 16 + fl) * 32 + fq * 8;
        fb[i] = Bs + (wcol + i * 16 + fl) * 32 + fq * 8;
    }

    f32x4 acc[4][4] = {};

    for (int k0 = kbeg; k0 < kend; k0 += 32) {
        __syncthreads();
        GL_LDS(ga0 + k0, la0);
        GL_LDS(ga1 + k0, la1);
        GL_LDS(gb0 + k0, lb0);
        GL_LDS(gb1 + k0, lb1);
        __syncthreads();

        bf16x8 av[4], bv[4];
        #pragma unroll
        for (int i = 0; i < 4; ++i) {
            av[i] = *(const bf16x8*)fa[i];
            bv[i] = *(const bf16x8*)fb[i];
        }
        #pragma unroll
        for (int mi = 0; mi < 4; ++mi)
            #pragma unroll
            for (int ni = 0; ni < 4; ++ni)
                acc[mi][ni] = __builtin_amdgcn_mfma_f32_16x16x32_bf16(
                    av[mi], bv[ni], acc[mi][ni], 0, 0, 0);
    }

    #pragma unroll
    for (int mi = 0; mi < 4; ++mi) {
        const int m = wrow + mi * 16 + fq * 4;
        #pragma unroll
        for (int ni = 0; ni < 4; ++ni) {
            const int n = wcol + ni * 16 + fl;
            const float bb = ADDBIAS ? bias[col0 + n] : 0.f;
            #pragma unroll
            for (int r = 0; r < 4; ++r) {
                float v = acc[mi][ni][r] + bb;
                if (RELU) v = fmaxf(v, 0.f);
                const size_t idx = (size_t)(row0 + m + r) * N + col0 + n;
                if (OUTBF) ((ushort_t*)Cout)[idx] = f2bf(v);
                else       ((float*)Cout)[idx]    = v;
            }
        }
    }
}

template<int RELU, int OUTBF>
__global__ __launch_bounds__(256)
void gemm_kernel(const ushort_t* __restrict__ A, const ushort_t* __restrict__ WT,
                 const float* __restrict__ bias, void* __restrict__ Cout,
                 int N, int K)
{
    gemm_body<RELU, OUTBF, 1>(A, WT, bias, Cout, N, K,
                              blockIdx.y * 128, blockIdx.x * 128, 0, K);
}

__global__ __launch_bounds__(256)
void gemm_splitk_kernel(const ushort_t* __restrict__ A, const ushort_t* __restrict__ WT,
                        float* __restrict__ parts, int N, int K, int kslice)
{
    const int z = blockIdx.z;
    float* out = parts + (size_t)z * kRows * N;
    gemm_body<0, 0, 0>(A, WT, nullptr, out, N, K,
                       blockIdx.y * 128, blockIdx.x * 128, z * kslice, (z + 1) * kslice);
}

__global__ __launch_bounds__(256)
void gemm_qkv_kernel(const ushort_t* __restrict__ A,
                     const ushort_t* wq, const ushort_t* wk, const ushort_t* wv,
                     const float* bq, const float* bk, const float* bv,
                     ushort_t* q, ushort_t* k, ushort_t* v)
{
    const ushort_t* WT; const float* bias; ushort_t* out;
    if (blockIdx.z == 0)      { WT = wq; bias = bq; out = q; }
    else if (blockIdx.z == 1) { WT = wk; bias = bk; out = k; }
    else                      { WT = wv; bias = bv; out = v; }
    gemm_body<0, 1, 1>(A, WT, bias, out, kD, kD,
                       blockIdx.y * 128, blockIdx.x * 128, 0, kD);
}

// ---------------------------------------------------------------------------
// Weight transpose + fp32->bf16:  W[K][N] -> WT[N][K] bf16.
// ---------------------------------------------------------------------------
struct WtDesc { const float* src; ushort_t* dst; int K; int N; };
struct WtArgs { WtDesc d[3]; };

__global__ __launch_bounds__(256)
void wt_kernel(WtArgs args)
{
    const WtDesc w = args.d[blockIdx.z];
    const int ktiles = w.K >> 6;
    const int kt = (blockIdx.x % ktiles) * 64;
    const int nt = (blockIdx.x / ktiles) * 64;
    if (nt >= w.N) return;

    __shared__ float T[64][65];
    const int tid = threadIdx.x;
    #pragma unroll
    for (int i = 0; i < 4; ++i) {
        const int e = tid + i * 256;
        const int r = e >> 4;
        const int c = (e & 15) * 4;
        const float4 f = *(const float4*)&w.src[(size_t)(kt + r) * w.N + nt + c];
        T[c + 0][r] = f.x; T[c + 1][r] = f.y; T[c + 2][r] = f.z; T[c + 3][r] = f.w;
    }
    __syncthreads();
    #pragma unroll
    for (int i = 0; i < 4; ++i) {
        const int e = tid + i * 256;
        const int n = e >> 4;
        const int kc = (e & 15) * 4;
        ushort4 o;
        o.x = f2bf(T[n][kc + 0]); o.y = f2bf(T[n][kc + 1]);
        o.z = f2bf(T[n][kc + 2]); o.w = f2bf(T[n][kc + 3]);
        *(ushort4*)&w.dst[(size_t)(nt + n) * w.K + kt + kc] = o;
    }
}

// fp32 -> bf16 elementwise
__global__ __launch_bounds__(256)
void cvt_kernel(const float* __restrict__ in, ushort_t* __restrict__ out, int n4)
{
    const int i = blockIdx.x * 256 + threadIdx.x;
    if (i < n4) {
        const float4 f = ((const float4*)in)[i];
        ushort4 o;
        o.x = f2bf(f.x); o.y = f2bf(f.y); o.z = f2bf(f.z); o.w = f2bf(f.w);
        ((ushort4*)out)[i] = o;
    }
}

// ---------------------------------------------------------------------------
// V transpose per head: vb[b*L+j][h*64+d] -> vt[(b*12+h)*64+d][j]
// ---------------------------------------------------------------------------
__global__ __launch_bounds__(256)
void vtrans_kernel(const ushort_t* __restrict__ vb, ushort_t* __restrict__ vt)
{
    const int bh = blockIdx.x;
    const int b = bh / kNH, h = bh - b * kNH;
    const int j0 = blockIdx.y * 64;
    __shared__ ushort_t T[64][72];

    const int tid = threadIdx.x;
    {
        const int jr = tid & 63;
        const int c0 = (tid >> 6) * 16;
        const ushort_t* sp = vb + (size_t)(b * kL + j0 + jr) * kD + h * kDK + c0;
        uint4 u0 = *(const uint4*)sp;
        uint4 u1 = *(const uint4*)(sp + 8);
        const ushort_t* e0 = (const ushort_t*)&u0;
        const ushort_t* e1 = (const ushort_t*)&u1;
        #pragma unroll
        for (int jj = 0; jj < 8; ++jj) {
            T[c0 + jj][jr]     = e0[jj];
            T[c0 + 8 + jj][jr] = e1[jj];
        }
    }
    __syncthreads();
    {
        const int dr = tid >> 2;
        const int jc = (tid & 3) * 16;
        ushort_t* dp = vt + (size_t)(bh * 64 + dr) * kL + j0 + jc;
        *(uint4*)dp       = *(const uint4*)&T[dr][jc];
        *(uint4*)(dp + 8) = *(const uint4*)&T[dr][jc + 8];
    }
}

// ---------------------------------------------------------------------------
// Relative-position bias table in MFMA-fragment order (see R5/R6 notes).
// The fixed softmax shift (-4) is FOLDED INTO THE TABLE: biasb = bias - 4.
// ---------------------------------------------------------------------------
__global__ __launch_bounds__(256, 4)
void bias_kernel(const float* __restrict__ sx, const float* __restrict__ sy,
                 const float* __restrict__ P1, const float* __restrict__ pb1,
                 const float* __restrict__ P2, const float* __restrict__ pb2,
                 ushort_t* __restrict__ biasb)
{
    const int bid = blockIdx.x;
    const int b  = bid >> 10;
    const int qt = (bid >> 4) & 63;
    const int kt = bid & 15;
    const int tid = threadIdx.x;

    __shared__ float P[32][16];       // [u] = {A,B,C,0, W2[0..11]}
    __shared__ float pb2l[12];
    __shared__ float qxl[16], qyl[16], kxl[64], kyl[64];
    __shared__ ushort_t Btile[12 * 1024];   // 24 KB

    if (tid < 32) {
        P[tid][0] = P1[tid];
        P[tid][1] = P1[32 + tid];
        P[tid][2] = pb1[tid];
        P[tid][3] = 0.f;
    }
    for (int e = tid; e < 384; e += 256) P[e / 12][4 + e % 12] = P2[e];
    if (tid < 12) pb2l[tid] = pb2[tid];
    if (tid < 16) { qxl[tid] = sx[b * kL + qt * 16 + tid];
                    qyl[tid] = sy[b * kL + qt * 16 + tid]; }
    if (tid < 64) { kxl[tid] = sx[b * kL + kt * 64 + tid];
                    kyl[tid] = sy[b * kL + kt * 64 + tid]; }
    __syncthreads();

    const int ri = tid >> 4;
    const int fl = tid & 15;
    const int fq = ri >> 2, r = ri & 3;
    const int lane16 = fq * 16 + fl;
    const float xi = qxl[ri], yi = qyl[ri];

    float rx[4], ry[4];
    #pragma unroll
    for (int n = 0; n < 4; ++n) {
        const int cj = n * 16 + fl;
        rx[n] = fminf(fmaxf(xi - kxl[cj], -1000.f), 1000.f) * 1e-3f;
        ry[n] = fminf(fmaxf(yi - kyl[cj], -1000.f), 1000.f) * 1e-3f;
    }

    float acc[4][12] = {};
    #pragma unroll 4
    for (int u = 0; u < 32; ++u) {
        const float4 pc = *(const float4*)&P[u][0];
        const float4 w0 = *(const float4*)&P[u][4];
        const float4 w1 = *(const float4*)&P[u][8];
        const float4 w2 = *(const float4*)&P[u][12];
        float t[4];
        #pragma unroll
        for (int n = 0; n < 4; ++n)
            t[n] = fmaxf(fmaf(rx[n], pc.x, fmaf(ry[n], pc.y, pc.z)), 0.f);
        #pragma unroll
        for (int n = 0; n < 4; ++n) {
            acc[n][0]  = fmaf(t[n], w0.x, acc[n][0]);
            acc[n][1]  = fmaf(t[n], w0.y, acc[n][1]);
            acc[n][2]  = fmaf(t[n], w0.z, acc[n][2]);
            acc[n][3]  = fmaf(t[n], w0.w, acc[n][3]);
            acc[n][4]  = fmaf(t[n], w1.x, acc[n][4]);
            acc[n][5]  = fmaf(t[n], w1.y, acc[n][5]);
            acc[n][6]  = fmaf(t[n], w1.z, acc[n][6]);
            acc[n][7]  = fmaf(t[n], w1.w, acc[n][7]);
            acc[n][8]  = fmaf(t[n], w2.x, acc[n][8]);
            acc[n][9]  = fmaf(t[n], w2.y, acc[n][9]);
            acc[n][10] = fmaf(t[n], w2.z, acc[n][10]);
            acc[n][11] = fmaf(t[n], w2.w, acc[n][11]);
        }
    }

    #pragma unroll
    for (int h = 0; h < 12; ++h) {
        const float pb = pb2l[h] - 4.0f;     // fixed softmax shift folded in
        #pragma unroll
        for (int n = 0; n < 4; ++n)
            Btile[h * 1024 + lane16 * 16 + n * 4 + r] = f2bf(acc[n][h] + pb);
    }
    __syncthreads();

    #pragma unroll
    for (int i = 0; i < 6; ++i) {
        const int off = (i * 256 + tid) * 8;
        const int h = off >> 10;
        const int inner = off & 1023;
        ushort_t* dst = biasb +
            (((size_t)(b * kNH + h) * 64 + qt) * 16 + kt) * 1024 + inner;
        *(uint4*)dst = *(const uint4*)&Btile[off];
    }
}

// ---------------------------------------------------------------------------
// MFMA flash attention (R11 structure: 4 waves/block = 4 K-splits, no in-loop
// barriers, in-block combine) with FIXED-SHIFT softmax:
//  P = exp(S/8 + bias - 4)  — the -4 lives in the bias table.  Scores are
//  bounded (|S| <~ 6; R7 validated this numerically: absmax identical), so no
//  running max is needed -> the per-tile chain has ZERO cross-lane ops and no
//  accO rescale.  l accumulates as per-lane partials; ONE 4-shuffle reduce
//  per wave at the end.  Combine weights: l_z / sum(l_z) (shared shift).
// ---------------------------------------------------------------------------
__global__ __launch_bounds__(256)
void attn_kernel(const ushort_t* __restrict__ qg, const ushort_t* __restrict__ kg,
                 const ushort_t* __restrict__ vt, const ushort_t* __restrict__ biasb,
                 ushort_t* __restrict__ og)
{
    const int bh = blockIdx.x;
    const int b  = bh / kNH, h = bh - b * kNH;
    const int qt = blockIdx.y;
    const int q0 = qt * 16;
    const int tid = threadIdx.x;
    const int z  = tid >> 6;          // wave = K-split
    const int lane = tid & 63;
    const int fl = lane & 15, fq = lane >> 4;

    __shared__ ushort_t Sp[4][16][72];   // per-wave P staging
    __shared__ ushort_t Ob[4][16][64];   // per-wave normalized O (bf16)
    __shared__ float    Ll[4][16];       // per-wave l per q-row

    const size_t qoff = (size_t)(b * kL + q0 + fl) * kD + h * kDK + fq * 8;
    const bf16x8 aq0 = *(const bf16x8*)(qg + qoff);
    const bf16x8 aq1 = *(const bf16x8*)(qg + qoff + 32);

    const ushort_t* kbase = kg + (size_t)(b * kL) * kD + h * kDK + fq * 8;
    const ushort_t* vbase = vt + (size_t)(bh * 64) * kL + fq * 8;
    const ushort_t* btile = biasb +
        ((size_t)(bh * 64 + qt) * 16 + z * 4) * 1024 + lane * 16;

    f32x4 accO[4] = {};
    float l_part[4] = {};             // per-lane partial row sums

    bf16x8 kc[4][2];
    uint4 bc0, bc1;
    {
        const int k0 = z * 256;
        #pragma unroll
        for (int n = 0; n < 4; ++n) {
            const ushort_t* kr = kbase + (size_t)(k0 + n * 16 + fl) * kD;
            kc[n][0] = *(const bf16x8*)kr;
            kc[n][1] = *(const bf16x8*)(kr + 32);
        }
        bc0 = *(const uint4*)btile;
        bc1 = *(const uint4*)(btile + 8);
    }

    #pragma unroll
    for (int t = 0; t < 4; ++t) {
        const int k0 = z * 256 + t * 64;

        bf16x8 vv[4][2];
        #pragma unroll
        for (int n = 0; n < 4; ++n) {
            const ushort_t* vr = vbase + (size_t)(n * 16 + fl) * kL + k0;
            vv[n][0] = *(const bf16x8*)vr;
            vv[n][1] = *(const bf16x8*)(vr + 32);
        }

        f32x4 S[4] = {};
        #pragma unroll
        for (int n = 0; n < 4; ++n) {
            S[n] = __builtin_amdgcn_mfma_f32_16x16x32_bf16(aq0, kc[n][0], S[n], 0, 0, 0);
            S[n] = __builtin_amdgcn_mfma_f32_16x16x32_bf16(aq1, kc[n][1], S[n], 0, 0, 0);
        }

        bf16x8 kn[4][2];
        uint4 bn0, bn1;
        if (t < 3) {
            #pragma unroll
            for (int n = 0; n < 4; ++n) {
                const ushort_t* kr = kbase + (size_t)(k0 + 64 + n * 16 + fl) * kD;
                kn[n][0] = *(const bf16x8*)kr;
                kn[n][1] = *(const bf16x8*)(kr + 32);
            }
            bn0 = *(const uint4*)(btile + (t + 1) * 1024);
            bn1 = *(const uint4*)(btile + (t + 1) * 1024 + 8);
        }

        ushort_t bu[16];
        *(uint4*)&bu[0] = bc0;
        *(uint4*)&bu[8] = bc1;

        // P = exp(S/8 + bias[-4 folded]); per-lane l partials; NO cross-lane
        #pragma unroll
        for (int n = 0; n < 4; ++n)
            #pragma unroll
            for (int r = 0; r < 4; ++r) {
                const float e = __expf(fmaf(S[n][r], 0.125f, bf2f(bu[n * 4 + r])));
                S[n][r] = e;
                l_part[r] += e;
            }

        // P -> wave-private LDS (C-layout -> A-layout); same-wave ordering
        // handled by lgkmcnt — no barrier.
        #pragma unroll
        for (int n = 0; n < 4; ++n)
            #pragma unroll
            for (int r = 0; r < 4; ++r)
                Sp[z][fq * 4 + r][n * 16 + fl] = f2bf(S[n][r]);

        const bf16x8 ap0 = *(const bf16x8*)&Sp[z][fl][fq * 8];
        const bf16x8 ap1 = *(const bf16x8*)&Sp[z][fl][32 + fq * 8];
        #pragma unroll
        for (int n = 0; n < 4; ++n) {
            accO[n] = __builtin_amdgcn_mfma_f32_16x16x32_bf16(ap0, vv[n][0], accO[n], 0, 0, 0);
            accO[n] = __builtin_amdgcn_mfma_f32_16x16x32_bf16(ap1, vv[n][1], accO[n], 0, 0, 0);
        }

        if (t < 3) {
            #pragma unroll
            for (int n = 0; n < 4; ++n) { kc[n][0] = kn[n][0]; kc[n][1] = kn[n][1]; }
            bc0 = bn0; bc1 = bn1;
        }
    }

    // one cross-lane l reduction per wave (16 lanes sharing fq)
    float l_full[4], inv[4];
    #pragma unroll
    for (int r = 0; r < 4; ++r) {
        float l = l_part[r];
        l += __shfl_xor(l, 1, 16);
        l += __shfl_xor(l, 2, 16);
        l += __shfl_xor(l, 4, 16);
        l += __shfl_xor(l, 8, 16);
        l_full[r] = l;
        inv[r] = 1.0f / l;
    }

    // stage normalized per-split O + l for the block-level combine
    #pragma unroll
    for (int n = 0; n < 4; ++n)
        #pragma unroll
        for (int r = 0; r < 4; ++r)
            Ob[z][fq * 4 + r][n * 16 + fl] = f2bf(accO[n][r] * inv[r]);
    if (fl == 0) {
        #pragma unroll
        for (int r = 0; r < 4; ++r)
            Ll[z][fq * 4 + r] = l_full[r];
    }
    __syncthreads();

    // combine: thread -> (row ri, dims d0..d0+3); weights l_z / sum(l_z)
    {
        const int ri = tid >> 4;
        const int d0 = (tid & 15) * 4;
        const float w0 = Ll[0][ri], w1 = Ll[1][ri], w2 = Ll[2][ri], w3 = Ll[3][ri];
        const float winv = 1.0f / (w0 + w1 + w2 + w3);
        const float c0 = w0 * winv, c1 = w1 * winv, c2 = w2 * winv, c3 = w3 * winv;

        ushort_t o[4];
        #pragma unroll
        for (int j = 0; j < 4; ++j)
            o[j] = f2bf(fmaf(c0, bf2f(Ob[0][ri][d0 + j]),
                        fmaf(c1, bf2f(Ob[1][ri][d0 + j]),
                        fmaf(c2, bf2f(Ob[2][ri][d0 + j]),
                             c3 * bf2f(Ob[3][ri][d0 + j])))));
        *(uint2*)&og[(size_t)(b * kL + q0 + ri) * kD + h * kDK + d0] = *(const uint2*)o;
    }
}

// ---------------------------------------------------------------------------
// Residual + split-K reduce + bias + LayerNorm.
// ---------------------------------------------------------------------------
template<int NPART, int DUAL>
__global__ __launch_bounds__(256)
void ln_kernel(const float* __restrict__ a, const float* __restrict__ parts,
               const float* __restrict__ bias,
               const float* __restrict__ g, const float* __restrict__ be,
               float* __restrict__ out, ushort_t* __restrict__ out_bf)
{
    const int row = blockIdx.x;
    const int tid = threadIdx.x;
    const float* pa = a + (size_t)row * kD;
    constexpr size_t NTOK = (size_t)kRows * kD;

    float v[3];
    float s = 0.f, sq = 0.f;
    #pragma unroll
    for (int i = 0; i < 3; ++i) {
        const int d = tid + i * 256;
        float t = pa[d] + bias[d];
        #pragma unroll
        for (int p = 0; p < NPART; ++p)
            t += parts[p * NTOK + (size_t)row * kD + d];
        v[i] = t;
        s  += t;
        sq += t * t;
    }
    #pragma unroll
    for (int off = 32; off > 0; off >>= 1) {
        s  += __shfl_down(s, off);
        sq += __shfl_down(sq, off);
    }
    __shared__ float bs[4], bq2[4];
    if ((tid & 63) == 0) { bs[tid >> 6] = s; bq2[tid >> 6] = sq; }
    __syncthreads();
    const float ts = bs[0] + bs[1] + bs[2] + bs[3];
    const float tq = bq2[0] + bq2[1] + bq2[2] + bq2[3];
    const float invn = 1.0f / (float)kD;
    const float mean = ts * invn;
    const float var  = tq * invn - mean * mean;
    const float rstd = rsqrtf(var + kEPS);

    float* po = out + (size_t)row * kD;
    #pragma unroll
    for (int i = 0; i < 3; ++i) {
        const int d = tid + i * 256;
        const float o = (v[i] - mean) * rstd * g[d] + be[d];
        po[d] = o;
        if (DUAL) out_bf[(size_t)row * kD + d] = f2bf(o);
    }
}

// ---------------------------------------------------------------------------
extern "C" void kernel_launch(void* const* d_in, const int* in_sizes, int n_in,
                              void* d_out, int out_size, void* d_ws, size_t ws_size,
                              hipStream_t stream)
{
    const float* src = (const float*)d_in[0];
    const float* sx  = (const float*)d_in[1];
    const float* sy  = (const float*)d_in[2];
    const float* Wq  = (const float*)d_in[3];  const float* bq  = (const float*)d_in[4];
    const float* Wk  = (const float*)d_in[5];  const float* bk  = (const float*)d_in[6];
    const float* Wv  = (const float*)d_in[7];  const float* bv  = (const float*)d_in[8];
    const float* Wo  = (const float*)d_in[9];  const float* bo  = (const float*)d_in[10];
    const float* P1  = (const float*)d_in[11]; const float* pb1 = (const float*)d_in[12];
    const float* P2  = (const float*)d_in[13]; const float* pb2 = (const float*)d_in[14];
    const float* W1  = (const float*)d_in[15]; const float* b1  = (const float*)d_in[16];
    const float* W2  = (const float*)d_in[17]; const float* b2  = (const float*)d_in[18];
    const float* g1  = (const float*)d_in[19]; const float* be1 = (const float*)d_in[20];
    const float* g2  = (const float*)d_in[21]; const float* be2 = (const float*)d_in[22];

    // ---- workspace arena (ushort units) ----
    constexpr size_t W768  = 768u * 768u;
    constexpr size_t W3072 = 768u * 3072u;
    constexpr size_t NTOK  = (size_t)kRows * kD;

    ushort_t* wsu = (ushort_t*)d_ws;
    ushort_t* wqT = wsu;
    ushort_t* wkT = wqT + W768;
    ushort_t* wvT = wkT + W768;
    ushort_t* qb  = wvT + W768;          // Q; dead after attn -> xbf
    ushort_t* kb  = qb + NTOK;
    ushort_t* vb  = kb + NTOK;
    ushort_t* sb  = vb + NTOK;           // src_bf -> attn out
    ushort_t* vtb = sb + NTOK;
    ushort_t* biasb = vtb + NTOK;        // 50 MB bias; reused after attn:
    ushort_t* woT   = biasb;
    ushort_t* w1T   = woT + W768;
    ushort_t* w2T   = w1T + W3072;
    float*    xb    = (float*)(w2T + W3072);
    ushort_t* h1bf  = (ushort_t*)(xb + NTOK);
    float*    s2p   = (float*)h1bf;
    float*    ff2p  = (float*)(h1bf + 4 * NTOK);
    ushort_t* xbf   = qb;

    const dim3 blk(256);

    WtArgs wa_early;
    wa_early.d[0] = { Wq, wqT, kD, kD };
    wa_early.d[1] = { Wk, wkT, kD, kD };
    wa_early.d[2] = { Wv, wvT, kD, kD };
    wt_kernel<<<dim3(144, 1, 3), blk, 0, stream>>>(wa_early);
    cvt_kernel<<<dim3((int)(NTOK / 4 / 256)), blk, 0, stream>>>(src, sb, (int)(NTOK / 4));
    bias_kernel<<<dim3(2048), blk, 0, stream>>>(sx, sy, P1, pb1, P2, pb2, biasb);

    gemm_qkv_kernel<<<dim3(kD / 128, kRows / 128, 3), blk, 0, stream>>>(
        sb, wqT, wkT, wvT, bq, bk, bv, qb, kb, vb);

    vtrans_kernel<<<dim3(2 * kNH, kL / 64), blk, 0, stream>>>(vb, vtb);

    // attention: 4 waves/block = 4 K-splits, in-block combine, O -> sb
    attn_kernel<<<dim3(2 * kNH, kL / 16), blk, 0, stream>>>(qb, kb, vtb, biasb, sb);

    WtArgs wa_late;
    wa_late.d[0] = { Wo, woT, kD,  kD  };
    wa_late.d[1] = { W1, w1T, kD,  kFF };
    wa_late.d[2] = { W2, w2T, kFF, kD  };
    wt_kernel<<<dim3(576, 1, 3), blk, 0, stream>>>(wa_late);

    gemm_splitk_kernel<<<dim3(kD / 128, kRows / 128, 2), blk, 0, stream>>>(
        sb, woT, s2p, kD, kD, kD / 2);

    ln_kernel<2, 1><<<dim3(kRows), blk, 0, stream>>>(src, s2p, bo, g1, be1, xb, xbf);

    gemm_kernel<1, 1><<<dim3(kFF / 128, kRows / 128), blk, 0, stream>>>(
        xbf, w1T, b1, h1bf, kFF, kD);

    gemm_splitk_kernel<<<dim3(kD / 128, kRows / 128, 3), blk, 0, stream>>>(
        h1bf, w2T, ff2p, kD, kFF, kFF / 3);

    ln_kernel<3, 0><<<dim3(kRows), blk, 0, stream>>>(xb, ff2p, b2, g2, be2,
                                                     (float*)d_out, nullptr);
}

// Round 14
// 290.948 us; speedup vs baseline: 1.0338x; 1.0338x over previous
//
#include <hip/hip_runtime.h>
#include <math.h>

typedef unsigned short ushort_t;
typedef __attribute__((ext_vector_type(8))) short bf16x8;
typedef __attribute__((ext_vector_type(4))) float f32x4;

constexpr int kD      = 768;
constexpr int kNH     = 12;
constexpr int kDK     = 64;
constexpr int kFF     = 3072;
constexpr int kL      = 1024;
constexpr int kRows   = 2048;     // B * L
constexpr float kEPS  = 1e-5f;

__device__ __forceinline__ ushort_t f2bf(float f) {
    union { float f; unsigned u; } v; v.f = f;
    unsigned r = (v.u + 0x7fffu + ((v.u >> 16) & 1u)) >> 16;
    return (ushort_t)r;
}
__device__ __forceinline__ float bf2f(ushort_t u) {
    union { unsigned u; float f; } v; v.u = ((unsigned)u) << 16; return v.f;
}

#define GL_LDS(gp, lp) __builtin_amdgcn_global_load_lds( \
    (const __attribute__((address_space(1))) void*)(gp), \
    (__attribute__((address_space(3))) void*)(lp), 16, 0, 0)

// ---------------------------------------------------------------------------
// bf16 MFMA GEMM body (m97 structure): 128x128 tile, BK=32, 4 waves.
// LDS supplied by caller (>= 16384 B).
// ---------------------------------------------------------------------------
template<int RELU, int OUTBF, int ADDBIAS>
__device__ __forceinline__ void gemm_body(const ushort_t* __restrict__ A,
                                          const ushort_t* __restrict__ WT,
                                          const float* __restrict__ bias,
                                          void* __restrict__ Cout,
                                          int N, int K, int row0, int col0,
                                          int kbeg, int kend, ushort_t* lds)
{
    ushort_t* As = lds;
    ushort_t* Bs = lds + 4096;

    const int tid  = threadIdx.x;
    const int lane = tid & 63;
    const int wave = tid >> 6;
    const int wrow = (wave & 1) * 64;
    const int wcol = (wave >> 1) * 64;

    const int srow = wave * 16 + (lane >> 2);
    const int sk   = (lane & 3) * 8;
    const ushort_t* ga0 = A  + (size_t)(row0 + srow)      * K + sk;
    const ushort_t* ga1 = A  + (size_t)(row0 + srow + 64) * K + sk;
    const ushort_t* gb0 = WT + (size_t)(col0 + srow)      * K + sk;
    const ushort_t* gb1 = WT + (size_t)(col0 + srow + 64) * K + sk;
    ushort_t* la0 = As + wave * 512;
    ushort_t* la1 = As + 2048 + wave * 512;
    ushort_t* lb0 = Bs + wave * 512;
    ushort_t* lb1 = Bs + 2048 + wave * 512;

    const int fl = lane & 15, fq = lane >> 4;
    const ushort_t* fa[4];
    const ushort_t* fb[4];
    #pragma unroll
    for (int i = 0; i < 4; ++i) {
        fa[i] = As + (wrow + i * 16 + fl) * 32 + fq * 8;
        fb[i] = Bs + (wcol + i * 16 + fl) * 32 + fq * 8;
    }

    f32x4 acc[4][4] = {};

    for (int k0 = kbeg; k0 < kend; k0 += 32) {
        __syncthreads();
        GL_LDS(ga0 + k0, la0);
        GL_LDS(ga1 + k0, la1);
        GL_LDS(gb0 + k0, lb0);
        GL_LDS(gb1 + k0, lb1);
        __syncthreads();

        bf16x8 av[4], bv[4];
        #pragma unroll
        for (int i = 0; i < 4; ++i) {
            av[i] = *(const bf16x8*)fa[i];
            bv[i] = *(const bf16x8*)fb[i];
        }
        #pragma unroll
        for (int mi = 0; mi < 4; ++mi)
            #pragma unroll
            for (int ni = 0; ni < 4; ++ni)
                acc[mi][ni] = __builtin_amdgcn_mfma_f32_16x16x32_bf16(
                    av[mi], bv[ni], acc[mi][ni], 0, 0, 0);
    }

    #pragma unroll
    for (int mi = 0; mi < 4; ++mi) {
        const int m = wrow + mi * 16 + fq * 4;
        #pragma unroll
        for (int ni = 0; ni < 4; ++ni) {
            const int n = wcol + ni * 16 + fl;
            const float bb = ADDBIAS ? bias[col0 + n] : 0.f;
            #pragma unroll
            for (int r = 0; r < 4; ++r) {
                float v = acc[mi][ni][r] + bb;
                if (RELU) v = fmaxf(v, 0.f);
                const size_t idx = (size_t)(row0 + m + r) * N + col0 + n;
                if (OUTBF) ((ushort_t*)Cout)[idx] = f2bf(v);
                else       ((float*)Cout)[idx]    = v;
            }
        }
    }
}

template<int RELU, int OUTBF>
__global__ __launch_bounds__(256)
void gemm_kernel(const ushort_t* __restrict__ A, const ushort_t* __restrict__ WT,
                 const float* __restrict__ bias, void* __restrict__ Cout,
                 int N, int K)
{
    __shared__ ushort_t lds[8192];
    gemm_body<RELU, OUTBF, 1>(A, WT, bias, Cout, N, K,
                              blockIdx.y * 128, blockIdx.x * 128, 0, K, lds);
}

__global__ __launch_bounds__(256)
void gemm_splitk_kernel(const ushort_t* __restrict__ A, const ushort_t* __restrict__ WT,
                        float* __restrict__ parts, int N, int K, int kslice)
{
    __shared__ ushort_t lds[8192];
    const int z = blockIdx.z;
    float* out = parts + (size_t)z * kRows * N;
    gemm_body<0, 0, 0>(A, WT, nullptr, out, N, K,
                       blockIdx.y * 128, blockIdx.x * 128,
                       z * kslice, (z + 1) * kslice, lds);
}

// ---------------------------------------------------------------------------
// Weight transpose tile: W[K][N] fp32 -> WT[N][K] bf16, 64x64 tile at (kt,nt).
// ---------------------------------------------------------------------------
__device__ __forceinline__ void wt_tile(const float* __restrict__ src,
                                        ushort_t* __restrict__ dst,
                                        int K, int N, int kt, int nt,
                                        float (*T)[65], int tid)
{
    #pragma unroll
    for (int i = 0; i < 4; ++i) {
        const int e = tid + i * 256;
        const int r = e >> 4;
        const int c = (e & 15) * 4;
        const float4 f = *(const float4*)&src[(size_t)(kt + r) * N + nt + c];
        T[c + 0][r] = f.x; T[c + 1][r] = f.y; T[c + 2][r] = f.z; T[c + 3][r] = f.w;
    }
    __syncthreads();
    #pragma unroll
    for (int i = 0; i < 4; ++i) {
        const int e = tid + i * 256;
        const int n = e >> 4;
        const int kc = (e & 15) * 4;
        ushort4 o;
        o.x = f2bf(T[n][kc + 0]); o.y = f2bf(T[n][kc + 1]);
        o.z = f2bf(T[n][kc + 2]); o.w = f2bf(T[n][kc + 3]);
        *(ushort4*)&dst[(size_t)(nt + n) * K + kt + kc] = o;
    }
}

// ---------------------------------------------------------------------------
// prep: blocks 0..431 = early weight transposes (Wq,Wk,Wv; 144 tiles each);
//       blocks 432..1967 = src fp32->bf16 (1536 blocks).
// ---------------------------------------------------------------------------
__global__ __launch_bounds__(256)
void prep_kernel(const float* __restrict__ Wq, const float* __restrict__ Wk,
                 const float* __restrict__ Wv,
                 ushort_t* wqT, ushort_t* wkT, ushort_t* wvT,
                 const float* __restrict__ src, ushort_t* __restrict__ sb)
{
    __shared__ float T[64][65];
    const int bid = blockIdx.x;
    const int tid = threadIdx.x;

    if (bid < 432) {
        const int wz = bid / 144, t = bid - wz * 144;
        const float* s = (wz == 0) ? Wq : (wz == 1) ? Wk : Wv;
        ushort_t*   d = (wz == 0) ? wqT : (wz == 1) ? wkT : wvT;
        wt_tile(s, d, kD, kD, (t % 12) * 64, (t / 12) * 64, T, tid);
    } else {
        const int i = (bid - 432) * 256 + tid;
        const float4 f = ((const float4*)src)[i];
        ushort4 o;
        o.x = f2bf(f.x); o.y = f2bf(f.y); o.z = f2bf(f.z); o.w = f2bf(f.w);
        ((ushort4*)sb)[i] = o;
    }
}

// ---------------------------------------------------------------------------
// Shared-memory layouts for the fused kernels.
// ---------------------------------------------------------------------------
struct BiasSmem {                 // 27312 B
    float P[32][16];              // [u] = {A,B,C,0, W2[0..11]}
    float pb2l[12];
    float qxl[16], qyl[16], kxl[64], kyl[64];
    ushort_t Btile[12 * 1024];
};
struct AttnSmem {                 // 17664 B
    ushort_t Sp[4][16][72];
    ushort_t Ob[4][16][64];
    float    Ll[4][16];
};

// ---------------------------------------------------------------------------
// Relative-position bias tile body (fragment-order table, -4 shift folded).
// bid in [0, 2048): b = bid>>10, qt = (bid>>4)&63, kt = bid&15.
// ---------------------------------------------------------------------------
__device__ __forceinline__ void bias_body(int bid, BiasSmem& S,
                 const float* __restrict__ sx, const float* __restrict__ sy,
                 const float* __restrict__ P1, const float* __restrict__ pb1,
                 const float* __restrict__ P2, const float* __restrict__ pb2,
                 ushort_t* __restrict__ biasb)
{
    const int b  = bid >> 10;
    const int qt = (bid >> 4) & 63;
    const int kt = bid & 15;
    const int tid = threadIdx.x;

    if (tid < 32) {
        S.P[tid][0] = P1[tid];
        S.P[tid][1] = P1[32 + tid];
        S.P[tid][2] = pb1[tid];
        S.P[tid][3] = 0.f;
    }
    for (int e = tid; e < 384; e += 256) S.P[e / 12][4 + e % 12] = P2[e];
    if (tid < 12) S.pb2l[tid] = pb2[tid];
    if (tid < 16) { S.qxl[tid] = sx[b * kL + qt * 16 + tid];
                    S.qyl[tid] = sy[b * kL + qt * 16 + tid]; }
    if (tid < 64) { S.kxl[tid] = sx[b * kL + kt * 64 + tid];
                    S.kyl[tid] = sy[b * kL + kt * 64 + tid]; }
    __syncthreads();

    const int ri = tid >> 4;
    const int fl = tid & 15;
    const int fq = ri >> 2, r = ri & 3;
    const int lane16 = fq * 16 + fl;
    const float xi = S.qxl[ri], yi = S.qyl[ri];

    float rx[4], ry[4];
    #pragma unroll
    for (int n = 0; n < 4; ++n) {
        const int cj = n * 16 + fl;
        rx[n] = fminf(fmaxf(xi - S.kxl[cj], -1000.f), 1000.f) * 1e-3f;
        ry[n] = fminf(fmaxf(yi - S.kyl[cj], -1000.f), 1000.f) * 1e-3f;
    }

    float acc[4][12] = {};
    #pragma unroll 4
    for (int u = 0; u < 32; ++u) {
        const float4 pc = *(const float4*)&S.P[u][0];
        const float4 w0 = *(const float4*)&S.P[u][4];
        const float4 w1 = *(const float4*)&S.P[u][8];
        const float4 w2 = *(const float4*)&S.P[u][12];
        float t[4];
        #pragma unroll
        for (int n = 0; n < 4; ++n)
            t[n] = fmaxf(fmaf(rx[n], pc.x, fmaf(ry[n], pc.y, pc.z)), 0.f);
        #pragma unroll
        for (int n = 0; n < 4; ++n) {
            acc[n][0]  = fmaf(t[n], w0.x, acc[n][0]);
            acc[n][1]  = fmaf(t[n], w0.y, acc[n][1]);
            acc[n][2]  = fmaf(t[n], w0.z, acc[n][2]);
            acc[n][3]  = fmaf(t[n], w0.w, acc[n][3]);
            acc[n][4]  = fmaf(t[n], w1.x, acc[n][4]);
            acc[n][5]  = fmaf(t[n], w1.y, acc[n][5]);
            acc[n][6]  = fmaf(t[n], w1.z, acc[n][6]);
            acc[n][7]  = fmaf(t[n], w1.w, acc[n][7]);
            acc[n][8]  = fmaf(t[n], w2.x, acc[n][8]);
            acc[n][9]  = fmaf(t[n], w2.y, acc[n][9]);
            acc[n][10] = fmaf(t[n], w2.z, acc[n][10]);
            acc[n][11] = fmaf(t[n], w2.w, acc[n][11]);
        }
    }

    #pragma unroll
    for (int h = 0; h < 12; ++h) {
        const float pb = S.pb2l[h] - 4.0f;    // fixed softmax shift folded in
        #pragma unroll
        for (int n = 0; n < 4; ++n)
            S.Btile[h * 1024 + lane16 * 16 + n * 4 + r] = f2bf(acc[n][h] + pb);
    }
    __syncthreads();

    #pragma unroll
    for (int i = 0; i < 6; ++i) {
        const int off = (i * 256 + tid) * 8;
        const int h = off >> 10;
        const int inner = off & 1023;
        ushort_t* dst = biasb +
            (((size_t)(b * kNH + h) * 64 + qt) * 16 + kt) * 1024 + inner;
        *(uint4*)dst = *(const uint4*)&S.Btile[off];
    }
}

// ---------------------------------------------------------------------------
// Fused QKV GEMM (blocks 0..287) + bias table (blocks 288..2335).
// Independent work; bias's VALU waves cover QKV's barrier drains (m114).
// ---------------------------------------------------------------------------
__global__ __launch_bounds__(256)
void qkv_bias_kernel(const ushort_t* __restrict__ A,
                     const ushort_t* wq, const ushort_t* wk, const ushort_t* wv,
                     const float* bq, const float* bk, const float* bv,
                     ushort_t* q, ushort_t* k, ushort_t* v,
                     const float* __restrict__ sx, const float* __restrict__ sy,
                     const float* __restrict__ P1, const float* __restrict__ pb1,
                     const float* __restrict__ P2, const float* __restrict__ pb2,
                     ushort_t* __restrict__ biasb)
{
    __shared__ __align__(16) char smem[sizeof(BiasSmem)];
    const int bid = blockIdx.x;

    if (bid < 288) {
        const int z = bid / 96, rem = bid - z * 96;
        const int bx = rem % 6, by = rem / 6;
        const ushort_t* WT; const float* bias; ushort_t* out;
        if (z == 0)      { WT = wq; bias = bq; out = q; }
        else if (z == 1) { WT = wk; bias = bk; out = k; }
        else             { WT = wv; bias = bv; out = v; }
        gemm_body<0, 1, 1>(A, WT, bias, out, kD, kD,
                           by * 128, bx * 128, 0, kD, (ushort_t*)smem);
    } else {
        bias_body(bid - 288, *(BiasSmem*)smem, sx, sy, P1, pb1, P2, pb2, biasb);
    }
}

// ---------------------------------------------------------------------------
// V transpose per head: vb[b*L+j][h*64+d] -> vt[(b*12+h)*64+d][j]
// ---------------------------------------------------------------------------
__global__ __launch_bounds__(256)
void vtrans_kernel(const ushort_t* __restrict__ vb, ushort_t* __restrict__ vt)
{
    const int bh = blockIdx.x;
    const int b = bh / kNH, h = bh - b * kNH;
    const int j0 = blockIdx.y * 64;
    __shared__ ushort_t T[64][72];

    const int tid = threadIdx.x;
    {
        const int jr = tid & 63;
        const int c0 = (tid >> 6) * 16;
        const ushort_t* sp = vb + (size_t)(b * kL + j0 + jr) * kD + h * kDK + c0;
        uint4 u0 = *(const uint4*)sp;
        uint4 u1 = *(const uint4*)(sp + 8);
        const ushort_t* e0 = (const ushort_t*)&u0;
        const ushort_t* e1 = (const ushort_t*)&u1;
        #pragma unroll
        for (int jj = 0; jj < 8; ++jj) {
            T[c0 + jj][jr]     = e0[jj];
            T[c0 + 8 + jj][jr] = e1[jj];
        }
    }
    __syncthreads();
    {
        const int dr = tid >> 2;
        const int jc = (tid & 3) * 16;
        ushort_t* dp = vt + (size_t)(bh * 64 + dr) * kL + j0 + jc;
        *(uint4*)dp       = *(const uint4*)&T[dr][jc];
        *(uint4*)(dp + 8) = *(const uint4*)&T[dr][jc + 8];
    }
}

// ---------------------------------------------------------------------------
// Fused attention (blocks 0..1535) + late weight transposes (1536..2831).
// Attn: R13 fixed-shift body (4 waves = 4 K-splits, no in-loop barriers,
// in-block combine).  wt blocks fill CUs during attn's tail.
// ---------------------------------------------------------------------------
constexpr size_t kAttnWtSmem =
    sizeof(AttnSmem) > sizeof(float) * 64 * 65 ? sizeof(AttnSmem)
                                               : sizeof(float) * 64 * 65;

__global__ __launch_bounds__(256)
void attn_wt_kernel(const ushort_t* __restrict__ qg, const ushort_t* __restrict__ kg,
                    const ushort_t* __restrict__ vt, const ushort_t* __restrict__ biasb,
                    ushort_t* __restrict__ og,
                    const float* __restrict__ Wo, const float* __restrict__ W1,
                    const float* __restrict__ W2,
                    ushort_t* woT, ushort_t* w1T, ushort_t* w2T)
{
    __shared__ __align__(16) char smem[kAttnWtSmem];
    const int bid = blockIdx.x;
    const int tid = threadIdx.x;

    if (bid >= 1536) {
        float (*T)[65] = (float(*)[65])smem;
        const int t = bid - 1536;
        if (t < 144)      wt_tile(Wo, woT, kD,  kD,  (t % 12) * 64, (t / 12) * 64, T, tid);
        else if (t < 720) { const int t2 = t - 144;
                            wt_tile(W1, w1T, kD,  kFF, (t2 % 12) * 64, (t2 / 12) * 64, T, tid); }
        else              { const int t2 = t - 720;
                            wt_tile(W2, w2T, kFF, kD,  (t2 % 48) * 64, (t2 / 48) * 64, T, tid); }
        return;
    }

    AttnSmem& S = *(AttnSmem*)smem;
    const int bh = bid >> 6;          // 0..23
    const int qt = bid & 63;
    const int b  = bh / kNH, h = bh - b * kNH;
    const int q0 = qt * 16;
    const int z  = tid >> 6;          // wave = K-split
    const int lane = tid & 63;
    const int fl = lane & 15, fq = lane >> 4;

    const size_t qoff = (size_t)(b * kL + q0 + fl) * kD + h * kDK + fq * 8;
    const bf16x8 aq0 = *(const bf16x8*)(qg + qoff);
    const bf16x8 aq1 = *(const bf16x8*)(qg + qoff + 32);

    const ushort_t* kbase = kg + (size_t)(b * kL) * kD + h * kDK + fq * 8;
    const ushort_t* vbase = vt + (size_t)(bh * 64) * kL + fq * 8;
    const ushort_t* btile = biasb +
        ((size_t)(bh * 64 + qt) * 16 + z * 4) * 1024 + lane * 16;

    f32x4 accO[4] = {};
    float l_part[4] = {};

    bf16x8 kc[4][2];
    uint4 bc0, bc1;
    {
        const int k0 = z * 256;
        #pragma unroll
        for (int n = 0; n < 4; ++n) {
            const ushort_t* kr = kbase + (size_t)(k0 + n * 16 + fl) * kD;
            kc[n][0] = *(const bf16x8*)kr;
            kc[n][1] = *(const bf16x8*)(kr + 32);
        }
        bc0 = *(const uint4*)btile;
        bc1 = *(const uint4*)(btile + 8);
    }

    #pragma unroll
    for (int t = 0; t < 4; ++t) {
        const int k0 = z * 256 + t * 64;

        bf16x8 vv[4][2];
        #pragma unroll
        for (int n = 0; n < 4; ++n) {
            const ushort_t* vr = vbase + (size_t)(n * 16 + fl) * kL + k0;
            vv[n][0] = *(const bf16x8*)vr;
            vv[n][1] = *(const bf16x8*)(vr + 32);
        }

        f32x4 Sv[4] = {};
        #pragma unroll
        for (int n = 0; n < 4; ++n) {
            Sv[n] = __builtin_amdgcn_mfma_f32_16x16x32_bf16(aq0, kc[n][0], Sv[n], 0, 0, 0);
            Sv[n] = __builtin_amdgcn_mfma_f32_16x16x32_bf16(aq1, kc[n][1], Sv[n], 0, 0, 0);
        }

        bf16x8 kn[4][2];
        uint4 bn0, bn1;
        if (t < 3) {
            #pragma unroll
            for (int n = 0; n < 4; ++n) {
                const ushort_t* kr = kbase + (size_t)(k0 + 64 + n * 16 + fl) * kD;
                kn[n][0] = *(const bf16x8*)kr;
                kn[n][1] = *(const bf16x8*)(kr + 32);
            }
            bn0 = *(const uint4*)(btile + (t + 1) * 1024);
            bn1 = *(const uint4*)(btile + (t + 1) * 1024 + 8);
        }

        ushort_t bu[16];
        *(uint4*)&bu[0] = bc0;
        *(uint4*)&bu[8] = bc1;

        #pragma unroll
        for (int n = 0; n < 4; ++n)
            #pragma unroll
            for (int r = 0; r < 4; ++r) {
                const float e = __expf(fmaf(Sv[n][r], 0.125f, bf2f(bu[n * 4 + r])));
                Sv[n][r] = e;
                l_part[r] += e;
            }

        #pragma unroll
        for (int n = 0; n < 4; ++n)
            #pragma unroll
            for (int r = 0; r < 4; ++r)
                S.Sp[z][fq * 4 + r][n * 16 + fl] = f2bf(Sv[n][r]);

        const bf16x8 ap0 = *(const bf16x8*)&S.Sp[z][fl][fq * 8];
        const bf16x8 ap1 = *(const bf16x8*)&S.Sp[z][fl][32 + fq * 8];
        #pragma unroll
        for (int n = 0; n < 4; ++n) {
            accO[n] = __builtin_amdgcn_mfma_f32_16x16x32_bf16(ap0, vv[n][0], accO[n], 0, 0, 0);
            accO[n] = __builtin_amdgcn_mfma_f32_16x16x32_bf16(ap1, vv[n][1], accO[n], 0, 0, 0);
        }

        if (t < 3) {
            #pragma unroll
            for (int n = 0; n < 4; ++n) { kc[n][0] = kn[n][0]; kc[n][1] = kn[n][1]; }
            bc0 = bn0; bc1 = bn1;
        }
    }

    float l_full[4], inv[4];
    #pragma unroll
    for (int r = 0; r < 4; ++r) {
        float l = l_part[r];
        l += __shfl_xor(l, 1, 16);
        l += __shfl_xor(l, 2, 16);
        l += __shfl_xor(l, 4, 16);
        l += __shfl_xor(l, 8, 16);
        l_full[r] = l;
        inv[r] = 1.0f / l;
    }

    #pragma unroll
    for (int n = 0; n < 4; ++n)
        #pragma unroll
        for (int r = 0; r < 4; ++r)
            S.Ob[z][fq * 4 + r][n * 16 + fl] = f2bf(accO[n][r] * inv[r]);
    if (fl == 0) {
        #pragma unroll
        for (int r = 0; r < 4; ++r)
            S.Ll[z][fq * 4 + r] = l_full[r];
    }
    __syncthreads();

    {
        const int ri = tid >> 4;
        const int d0 = (tid & 15) * 4;
        const float w0 = S.Ll[0][ri], w1 = S.Ll[1][ri], w2 = S.Ll[2][ri], w3 = S.Ll[3][ri];
        const float winv = 1.0f / (w0 + w1 + w2 + w3);
        const float c0 = w0 * winv, c1 = w1 * winv, c2 = w2 * winv, c3 = w3 * winv;

        ushort_t o[4];
        #pragma unroll
        for (int j = 0; j < 4; ++j)
            o[j] = f2bf(fmaf(c0, bf2f(S.Ob[0][ri][d0 + j]),
                        fmaf(c1, bf2f(S.Ob[1][ri][d0 + j]),
                        fmaf(c2, bf2f(S.Ob[2][ri][d0 + j]),
                             c3 * bf2f(S.Ob[3][ri][d0 + j])))));
        *(uint2*)&og[(size_t)(b * kL + q0 + ri) * kD + h * kDK + d0] = *(const uint2*)o;
    }
}

// ---------------------------------------------------------------------------
// Residual + split-K reduce + bias + LayerNorm.
// ---------------------------------------------------------------------------
template<int NPART, int DUAL>
__global__ __launch_bounds__(256)
void ln_kernel(const float* __restrict__ a, const float* __restrict__ parts,
               const float* __restrict__ bias,
               const float* __restrict__ g, const float* __restrict__ be,
               float* __restrict__ out, ushort_t* __restrict__ out_bf)
{
    const int row = blockIdx.x;
    const int tid = threadIdx.x;
    const float* pa = a + (size_t)row * kD;
    constexpr size_t NTOK = (size_t)kRows * kD;

    float v[3];
    float s = 0.f, sq = 0.f;
    #pragma unroll
    for (int i = 0; i < 3; ++i) {
        const int d = tid + i * 256;
        float t = pa[d] + bias[d];
        #pragma unroll
        for (int p = 0; p < NPART; ++p)
            t += parts[p * NTOK + (size_t)row * kD + d];
        v[i] = t;
        s  += t;
        sq += t * t;
    }
    #pragma unroll
    for (int off = 32; off > 0; off >>= 1) {
        s  += __shfl_down(s, off);
        sq += __shfl_down(sq, off);
    }
    __shared__ float bs[4], bq2[4];
    if ((tid & 63) == 0) { bs[tid >> 6] = s; bq2[tid >> 6] = sq; }
    __syncthreads();
    const float ts = bs[0] + bs[1] + bs[2] + bs[3];
    const float tq = bq2[0] + bq2[1] + bq2[2] + bq2[3];
    const float invn = 1.0f / (float)kD;
    const float mean = ts * invn;
    const float var  = tq * invn - mean * mean;
    const float rstd = rsqrtf(var + kEPS);

    float* po = out + (size_t)row * kD;
    #pragma unroll
    for (int i = 0; i < 3; ++i) {
        const int d = tid + i * 256;
        const float o = (v[i] - mean) * rstd * g[d] + be[d];
        po[d] = o;
        if (DUAL) out_bf[(size_t)row * kD + d] = f2bf(o);
    }
}

// ---------------------------------------------------------------------------
extern "C" void kernel_launch(void* const* d_in, const int* in_sizes, int n_in,
                              void* d_out, int out_size, void* d_ws, size_t ws_size,
                              hipStream_t stream)
{
    const float* src = (const float*)d_in[0];
    const float* sx  = (const float*)d_in[1];
    const float* sy  = (const float*)d_in[2];
    const float* Wq  = (const float*)d_in[3];  const float* bq  = (const float*)d_in[4];
    const float* Wk  = (const float*)d_in[5];  const float* bk  = (const float*)d_in[6];
    const float* Wv  = (const float*)d_in[7];  const float* bv  = (const float*)d_in[8];
    const float* Wo  = (const float*)d_in[9];  const float* bo  = (const float*)d_in[10];
    const float* P1  = (const float*)d_in[11]; const float* pb1 = (const float*)d_in[12];
    const float* P2  = (const float*)d_in[13]; const float* pb2 = (const float*)d_in[14];
    const float* W1  = (const float*)d_in[15]; const float* b1  = (const float*)d_in[16];
    const float* W2  = (const float*)d_in[17]; const float* b2  = (const float*)d_in[18];
    const float* g1  = (const float*)d_in[19]; const float* be1 = (const float*)d_in[20];
    const float* g2  = (const float*)d_in[21]; const float* be2 = (const float*)d_in[22];

    // ---- workspace arena (ushort units) ----
    constexpr size_t W768  = 768u * 768u;
    constexpr size_t W3072 = 768u * 3072u;
    constexpr size_t NTOK  = (size_t)kRows * kD;

    ushort_t* wsu = (ushort_t*)d_ws;
    ushort_t* wqT = wsu;
    ushort_t* wkT = wqT + W768;
    ushort_t* wvT = wkT + W768;
    ushort_t* qb  = wvT + W768;          // Q; dead after attn -> xbf
    ushort_t* kb  = qb + NTOK;
    ushort_t* vb  = kb + NTOK;
    ushort_t* sb  = vb + NTOK;           // src_bf -> attn out
    ushort_t* vtb = sb + NTOK;
    ushort_t* biasb = vtb + NTOK;        // 50 MB bias; reused after attn:
    ushort_t* woT   = biasb;
    ushort_t* w1T   = woT + W768;
    ushort_t* w2T   = w1T + W3072;
    float*    xb    = (float*)(w2T + W3072);
    ushort_t* h1bf  = (ushort_t*)(xb + NTOK);
    float*    s2p   = (float*)h1bf;
    float*    ff2p  = (float*)(h1bf + 4 * NTOK);
    ushort_t* xbf   = qb;

    const dim3 blk(256);

    // 1. early weight transposes + src->bf16 (fused)
    prep_kernel<<<dim3(1968), blk, 0, stream>>>(Wq, Wk, Wv, wqT, wkT, wvT, src, sb);

    // 2. QKV projection + bias table (fused, independent work co-resident)
    qkv_bias_kernel<<<dim3(2336), blk, 0, stream>>>(
        sb, wqT, wkT, wvT, bq, bk, bv, qb, kb, vb,
        sx, sy, P1, pb1, P2, pb2, biasb);

    // 3. V transpose per head
    vtrans_kernel<<<dim3(2 * kNH, kL / 64), blk, 0, stream>>>(vb, vtb);

    // 4. attention + late weight transposes (fused; wt fills attn's tail)
    //    NOTE: woT/w1T/w2T alias the bias region — attn reads biasb while wt
    //    writes woT/w1T/w2T.  biasb layout: per-(bh) stride 64*16*1024 ushorts;
    //    woT..w2T occupy the first 5.9M ushorts = the first 5.7 (b,h) slots of
    //    bias — which belong to b=0,h=0..5.  CONFLICT!  -> wt uses a separate
    //    scratch region placed AFTER ff2p instead (see below).
    attn_wt_kernel<<<dim3(2832), blk, 0, stream>>>(
        qb, kb, vtb, biasb, sb, Wo, W1, W2,
        (ushort_t*)(ff2p + 3 * NTOK),
        (ushort_t*)(ff2p + 3 * NTOK) + W768,
        (ushort_t*)(ff2p + 3 * NTOK) + W768 + W3072);

    ushort_t* woT2 = (ushort_t*)(ff2p + 3 * NTOK);
    ushort_t* w1T2 = woT2 + W768;
    ushort_t* w2T2 = w1T2 + W3072;

    // 5. out-projection, split-K=2 -> fp32 partials
    gemm_splitk_kernel<<<dim3(kD / 128, kRows / 128, 2), blk, 0, stream>>>(
        sb, woT2, s2p, kD, kD, kD / 2);

    // 6. LN1: x = LN(src + bo + partials), fp32 + bf16
    ln_kernel<2, 1><<<dim3(kRows), blk, 0, stream>>>(src, s2p, bo, g1, be1, xb, xbf);

    // 7. FFN1: relu(x @ W1 + b1) -> bf16
    gemm_kernel<1, 1><<<dim3(kFF / 128, kRows / 128), blk, 0, stream>>>(
        xbf, w1T2, b1, h1bf, kFF, kD);

    // 8. FFN2, split-K=3 -> fp32 partials
    gemm_splitk_kernel<<<dim3(kD / 128, kRows / 128, 3), blk, 0, stream>>>(
        h1bf, w2T2, ff2p, kD, kFF, kFF / 3);

    // 9. LN2: out = LN(x + b2 + partials)
    ln_kernel<3, 0><<<dim3(kRows), blk, 0, stream>>>(xb, ff2p, b2, g2, be2,
                                                     (float*)d_out, nullptr);
}